// Round 1
// baseline (354.746 us; speedup 1.0000x reference)
//
#include <hip/hip_runtime.h>

#define MARGIN 0.5f

// x: [V, C, T] fp32, T=128 contiguous. target: [V, C] int.
// Each half-wave (32 lanes) processes one row of 128 floats as float4/lane.
// Sum max(0, x - pos + margin) over ALL t, then subtract the exact 0.5
// contribution of t==target once per row. Scaled atomicAdd per block.
__global__ __launch_bounds__(256) void margin_loss_kernel(
    const float* __restrict__ x,
    const int* __restrict__ target,
    float* __restrict__ out,
    int rows,          // V*C
    float inv_cnt)     // 1 / (V*C*(T-1))
{
    const int T = 128;
    const int tid = threadIdx.x;
    const int lane = tid & 63;          // lane in wave (wave64)
    const int wave = tid >> 6;          // wave in block: 0..3
    const int gl = lane & 31;           // lane within half-wave group
    const int group = lane >> 5;        // which half-wave (0/1)

    // half-wave slots across the whole grid
    const int slot = ((blockIdx.x * 4 + wave) << 1) + group;
    const int total_slots = gridDim.x * 8;

    float acc = 0.0f;
    int rows_handled = 0;

    for (int row = slot; row < rows; row += total_slots) {
        const float4 v = ((const float4*)(x + (size_t)row * T))[gl];
        const int tgt = target[row];    // uniform within the half-wave (broadcast)

        // branchless select of component (tgt & 3) from own float4
        float lo = (tgt & 1) ? v.y : v.x;
        float hi = (tgt & 1) ? v.w : v.z;
        float comp = (tgt & 2) ? hi : lo;
        // broadcast from the lane holding element tgt (within this half-wave)
        float pos = __shfl(comp, (group << 5) + (tgt >> 2), 64);

        const float b = MARGIN - pos;
        acc += fmaxf(v.x + b, 0.0f) + fmaxf(v.y + b, 0.0f)
             + fmaxf(v.z + b, 0.0f) + fmaxf(v.w + b, 0.0f);
        rows_handled++;
    }

    // remove the t==target term: it is exactly MARGIN per row
    if (gl == 0) acc -= MARGIN * (float)rows_handled;

    // wave reduction (64 lanes)
    #pragma unroll
    for (int off = 32; off > 0; off >>= 1)
        acc += __shfl_down(acc, off, 64);

    __shared__ float s[4];
    if (lane == 0) s[wave] = acc;
    __syncthreads();
    if (tid == 0) {
        float total = (s[0] + s[1]) + (s[2] + s[3]);
        atomicAdd(out, total * inv_cnt);
    }
}

extern "C" void kernel_launch(void* const* d_in, const int* in_sizes, int n_in,
                              void* d_out, int out_size, void* d_ws, size_t ws_size,
                              hipStream_t stream) {
    const float* x = (const float*)d_in[0];
    const int* target = (const int*)d_in[1];
    float* out = (float*)d_out;

    const int T = 128;
    const int rows = in_sizes[1];              // V*C = 524288
    const long long cnt = (long long)rows * (T - 1);
    const float inv_cnt = 1.0f / (float)cnt;

    hipMemsetAsync(out, 0, sizeof(float), stream);

    const int blocks = 1024;                   // 8192 half-wave slots, 64 iters
    margin_loss_kernel<<<blocks, 256, 0, stream>>>(x, target, out, rows, inv_cnt);
}